// Round 5
// baseline (32.167 us; speedup 1.0000x reference)
//
#include <hip/hip_runtime.h>
#include <hip/hip_bf16.h>

// out[b,h,i,j] = mask[b,h,i,j] - bias[h, i-j]
// bias depends only on d = i-j+1023 -> 8 x 2047 table (64 KiB), stored
// REVERSED (rtab[h][1023-i+j]) so a row's j-sweep is an ascending window.
//
// Apply kernel: one block per (h, i0..i0+3, b=0..1) tile = 8 output rows.
// The 4 i-rows (and both batches) share one 1027-float window -> stage it
// into LDS once, then steady-state VMEM is exactly load16B+store16B per
// thread-iter (the table gather is off the VMEM path).

#define L_SEQ 1024
#define NDIAG (2 * L_SEQ - 1)   // 2047
#define NH 8
#define DIM 64

typedef float f32x4 __attribute__((ext_vector_type(4)));

__device__ __forceinline__ float silu_f(float x) {
    return x / (1.0f + __expf(-x));
}

// 4 diagonals per 256-thread block; 64 lanes per diagonal.
__global__ __launch_bounds__(256) void build_bias_table(
    const float* __restrict__ W0, const float* __restrict__ b0,
    const float* __restrict__ W1, const float* __restrict__ b1,
    const float* __restrict__ W2, const float* __restrict__ b2,
    const float* __restrict__ Wf, const float* __restrict__ bf,
    float* __restrict__ rtab /* [NH][NDIAG], reversed */) {
    const int g = threadIdx.x >> 6;      // diag group 0..3
    const int t = threadIdx.x & 63;      // 0..63
    const int d = blockIdx.x * 4 + g;    // 0..2047 (guard 2047)
    const float rel = (float)(d - (L_SEQ - 1));

    __shared__ float sh[4][DIM];

    float h = silu_f(rel * W0[t] + b0[t]);
    sh[g][t] = h;
    __syncthreads();

    float acc = b1[t];
    #pragma unroll
    for (int k = 0; k < DIM; ++k) acc += sh[g][k] * W1[k * DIM + t];
    float h1 = silu_f(acc);
    __syncthreads();
    sh[g][t] = h1;
    __syncthreads();

    acc = b2[t];
    #pragma unroll
    for (int k = 0; k < DIM; ++k) acc += sh[g][k] * W2[k * DIM + t];
    float h2 = silu_f(acc);
    __syncthreads();
    sh[g][t] = h2;
    __syncthreads();

    if (t < NH && d < NDIAG) {
        float a = bf[t];
        #pragma unroll
        for (int k = 0; k < DIM; ++k) a += sh[g][k] * Wf[k * NH + t];
        rtab[t * NDIAG + (NDIAG - 1 - d)] = a;
    }
}

// pad-swizzle: +1 float per 32 -> stride-16B reads become free 2-way
__device__ __forceinline__ int SW(int k) { return k + (k >> 5); }
#define WIN 1027                       // 1024 + 3 (4 shifted i-windows)
#define LDS_FLOATS (WIN + (WIN >> 5) + 1)

__global__ __launch_bounds__(256) void apply_bias(
    const f32x4* __restrict__ mask, const float* __restrict__ rtab,
    f32x4* __restrict__ out) {
    const int blk  = blockIdx.x;         // 0..2047
    const int h    = blk >> 8;           // 0..7
    const int i0   = (blk & 255) << 2;   // 0,4,...,1020
    const int t    = threadIdx.x;

    __shared__ float w[LDS_FLOATS];

    // window for rows i0..i0+3 starts at rtab[h][1023-(i0+3)], len 1027
    const float* src = rtab + h * NDIAG + (1020 - i0);
    for (int k = t; k < WIN; k += 256) w[SW(k)] = src[k];
    __syncthreads();

    #pragma unroll
    for (int r = 0; r < 4; ++r) {
        const int off = (3 - r) + (t << 2);   // row i0+r's shift in window
        const float v0 = w[SW(off + 0)];
        const float v1 = w[SW(off + 1)];
        const float v2 = w[SW(off + 2)];
        const float v3 = w[SW(off + 3)];
        const int i = i0 + r;
        #pragma unroll
        for (int b = 0; b < 2; ++b) {
            const int idx = ((b * NH + h) * L_SEQ + i) * 256 + t;
            const f32x4 m = mask[idx];
            f32x4 o;
            o.x = m.x - v0;
            o.y = m.y - v1;
            o.z = m.z - v2;
            o.w = m.w - v3;
            out[idx] = o;
        }
    }
}

extern "C" void kernel_launch(void* const* d_in, const int* in_sizes, int n_in,
                              void* d_out, int out_size, void* d_ws, size_t ws_size,
                              hipStream_t stream) {
    const float* mask = (const float*)d_in[0];
    const float* W0 = (const float*)d_in[4];
    const float* b0 = (const float*)d_in[5];
    const float* W1 = (const float*)d_in[6];
    const float* b1 = (const float*)d_in[7];
    const float* W2 = (const float*)d_in[8];
    const float* b2 = (const float*)d_in[9];
    const float* Wf = (const float*)d_in[10];
    const float* bf = (const float*)d_in[11];
    float* out = (float*)d_out;

    float* rtab = (float*)d_ws;   // NH * NDIAG floats = 64 KiB

    build_bias_table<<<(NDIAG + 3) / 4, 256, 0, stream>>>(
        W0, b0, W1, b1, W2, b2, Wf, bf, rtab);

    // 8 heads x 256 i-tiles = 2048 blocks; each handles 8 rows (4 i x 2 b)
    apply_bias<<<2048, 256, 0, stream>>>(
        (const f32x4*)mask, rtab, (f32x4*)out);
}